// Round 8
// baseline (935.596 us; speedup 1.0000x reference)
//
#include <hip/hip_runtime.h>
#include <hip/hip_bf16.h>

typedef _Float16 f16x8 __attribute__((ext_vector_type(8)));
typedef _Float16 f16x4 __attribute__((ext_vector_type(4)));
typedef float f32x4 __attribute__((ext_vector_type(4)));

__device__ __forceinline__ float tanh_fast(float x) {
  float e = __expf(2.0f * x);
  return 1.0f - 2.0f * __builtin_amdgcn_rcpf(e + 1.0f);
}
__device__ __forceinline__ float sigmoid_fast(float x) {
  return __builtin_amdgcn_rcpf(1.0f + __expf(-x));
}

// ---------------- K0: weight prep (unchanged) ----------------
// Fragment tiles of 512 hw. PI k-order (W2, Wq1): lane l elem j holds
// B[k = kt*32 + pi(q,j)][col = nt*16 + l15], pi(q,j) = q*4 + (j&3) + 16*(j>>2).
// Plain k-order (Wq2, W1): k = q*8 + j.
// V2p tile = kt*64 + nt; T1p tile = kt*16 + nt; T2p tile = nt*8 + kt.
__global__ __launch_bounds__(256) void prep_weights(
    const float* __restrict__ W1, const float* __restrict__ W2,
    const float* __restrict__ Wq1, const float* __restrict__ Wq2,
    _Float16* __restrict__ V1p, _Float16* __restrict__ V2p,
    _Float16* __restrict__ T1p, _Float16* __restrict__ T2p) {
  __shared__ float S[32 * 33];
  int b = blockIdx.x, t = threadIdx.x;
  if (b < 2624) {
    const float* in; _Float16* out; int N, nc0, tile, use_pi;
    if (b < 2048) {        // W2 [32][1024][32]: h, ntl, kt  (PI)
      int h = b >> 6, rem = b & 63, ntl = rem >> 5, kt = rem & 31;
      in = W2 + (size_t)h * 32768 + (size_t)kt * 32 * 32;
      N = 32; nc0 = ntl * 16;
      out = V2p; tile = kt * 64 + (h * 2 + ntl); use_pi = 1;
    } else if (b < 2560) { // Wq1 [1024][256]  (PI)
      int i = b - 2048, nt = i >> 5, kt = i & 31;
      in = Wq1 + (size_t)kt * 32 * 256; N = 256; nc0 = nt * 16;
      out = T1p; tile = kt * 16 + nt; use_pi = 1;
    } else {               // Wq2 [256][128]  (plain)
      int i = b - 2560, nt = i >> 3, kt = i & 7;
      in = Wq2 + (size_t)kt * 32 * 128; N = 128; nc0 = nt * 16;
      out = T2p; tile = nt * 8 + kt; use_pi = 0;
    }
    if (t < 128) {
      int r = t >> 2, c4 = (t & 3) * 4;
      const float4 v = *(const float4*)(in + (size_t)r * N + nc0 + c4);
      S[r * 17 + c4 + 0] = v.x; S[r * 17 + c4 + 1] = v.y;
      S[r * 17 + c4 + 2] = v.z; S[r * 17 + c4 + 3] = v.w;
    }
    __syncthreads();
    if (t < 128) {
      int w2 = t >> 6, l = t & 63, q = l >> 4, l15 = l & 15;
      f16x4 o;
#pragma unroll
      for (int jj = 0; jj < 4; ++jj) {
        int kl = use_pi ? (q * 4 + jj + w2 * 16) : (q * 8 + w2 * 4 + jj);
        o[jj] = (_Float16)S[kl * 17 + l15];
      }
      *(f16x4*)(out + (size_t)tile * 512 + l * 8 + w2 * 4) = o;
    }
  } else {                 // W1 [32][32][32]: one block per head h (plain)
    int h = b - 2624;
    const float* in = W1 + h * 1024;
    int cc = t & 31, rr8 = t >> 5;
#pragma unroll
    for (int p = 0; p < 4; ++p) {
      int r = rr8 + p * 8;
      S[cc * 33 + r] = in[r * 32 + cc];
    }
    __syncthreads();
    if (t < 128) {
      int ntl = t >> 6, l = t & 63, q = l >> 4, l15 = l & 15;
      f16x8 o;
#pragma unroll
      for (int j = 0; j < 8; ++j)
        o[j] = (_Float16)S[(ntl * 16 + l15) * 33 + q * 8 + j];
      *(f16x8*)(V1p + (size_t)(h * 2 + ntl) * 512 + l * 8) = o;
    }
  }
}

// ---------------- K12Q: fully fused ripple1+ripple2+q-network ----------------
// Block = 64 rows x 1024 cols, 512 threads = 8 waves; wave = 64 rows x 128
// cols (nt0 = w*8), acc[4][8]. K-loop: round-6 verbatim (4-phase, staggered
// producer, setprio). TAIL: instead of writing x2 to gmem for a separate k3,
// the block's registers hold the full [64 x 1024] x2 tile -> run the entire
// q-network in-block:
//   pass A: waves 0..3 -> tanh'd kc2 0..15 frags into x2h (aliases dead XB,
//           byte-identical tile layout to old x2p), q1-GEMM kt 0..15;
//   pass B: waves 4..7 -> kc2 16..31, q1-GEMM kt 16..31;
//   LN-256+relu -> y1h; y2-GEMM (T2p, 1 n-tile/wave); LN-128+relu+Wq3 -> out.
// Deletes k3, the x2 workspace, and the slice loop (single 2048-block launch;
// ~512 MB of gmem traffic eliminated). LDS ~106.5 KB -> 1 block/CU (register
// cap 2 waves/SIMD binds anyway). launch_bounds MUST stay (512,2).
__global__ __launch_bounds__(512, 2) void k12q(
    const float* __restrict__ state, const float* __restrict__ action,
    const _Float16* __restrict__ v1p, const float* __restrict__ b1,
    const float* __restrict__ g1,
    const _Float16* __restrict__ v2p, const float* __restrict__ b2,
    const float* __restrict__ g2,
    const _Float16* __restrict__ t1p, const _Float16* __restrict__ t2p,
    const float* __restrict__ bq1, const float* __restrict__ ln1g,
    const float* __restrict__ ln1b,
    const float* __restrict__ bq2, const float* __restrict__ ln2g,
    const float* __restrict__ ln2b,
    const float* __restrict__ wq3, const float* __restrict__ bq3,
    float* __restrict__ out) {
  __shared__ __align__(16) _Float16 SA[64 * 40];         // 5 KB
  __shared__ __align__(16) _Float16 XB[2][8 * 4 * 512];  // 2 x 32 KB (K-loop); x2h (tail)
  __shared__ __align__(16) _Float16 y1h[64 * 264];       // 33.8 KB
  __shared__ float redA[64 * 8], redB[64 * 8];           // 4 KB
  __shared__ float meanv[64], rstdv[64];                 // 0.5 KB
  _Float16* x2h = &XB[0][0];                             // 64 tiles x 1KB alias

  int bm = blockIdx.x;
  int t = threadIdx.x, w = t >> 6, l = t & 63, q = l >> 4, l15 = l & 15;
  int m0 = bm * 64;

  {  // stage sa tile [64][32] fp16, stride 40; 8 threads/row (4 floats each)
    int r = t >> 3, qq = t & 7;
    size_t grow = (size_t)(m0 + r);
    const float* src = (qq < 6) ? (state + grow * 24 + qq * 4)
                                : (action + grow * 8 + (qq - 6) * 4);
    float4 v = *(const float4*)src;
    f16x4 h;
    h[0] = (_Float16)v.x; h[1] = (_Float16)v.y;
    h[2] = (_Float16)v.z; h[3] = (_Float16)v.w;
    *(f16x4*)&SA[r * 40 + qq * 4] = h;
  }
  __syncthreads();

  // loop-invariant sa fragments (B operand of producer MFMAs), 64 rows
  f16x8 asa[4];
#pragma unroll
  for (int p = 0; p < 4; ++p)
    asa[p] = *(const f16x8*)&SA[(p * 16 + l15) * 40 + q * 8];

  const int nt0 = w * 8;
  const _Float16* bBase = v2p + (size_t)nt0 * 512 + (size_t)l * 8;
  f32x4 acc[4][8] = {};

  auto produce = [&](int h, int buf) {
    f16x8 rb0 = *(const f16x8*)(v1p + (size_t)(2 * h) * 512 + l * 8);
    f16x8 rb1 = *(const f16x8*)(v1p + (size_t)(2 * h + 1) * 512 + l * 8);
    float sg = sigmoid_fast(g1[h]);
    f32x4 bs0 = *(const f32x4*)(b1 + h * 32 + q * 4);
    f32x4 bs1 = *(const f32x4*)(b1 + h * 32 + 16 + q * 4);
    _Float16* bw = &XB[buf][(size_t)((h & 7) * 4) * 512 + l * 8];
#pragma unroll
    for (int pp = 0; pp < 4; ++pp) {
      f32x4 d0 = {}, d1 = {};
      d0 = __builtin_amdgcn_mfma_f32_16x16x32_f16(rb0, asa[pp], d0, 0, 0, 0);
      d1 = __builtin_amdgcn_mfma_f32_16x16x32_f16(rb1, asa[pp], d1, 0, 0, 0);
      f16x8 o;
#pragma unroll
      for (int r = 0; r < 4; ++r) {
        o[r]     = (_Float16)(tanh_fast(d0[r] + bs0[r]) * sg);
        o[4 + r] = (_Float16)(tanh_fast(d1[r] + bs1[r]) * sg);
      }
      *(f16x8*)(bw + (size_t)pp * 512) = o;
    }
  };

  // prologue
  f16x8 bb0[4], bb1v[4];
#pragma unroll
  for (int n2 = 0; n2 < 4; ++n2)
    bb0[n2] = *(const f16x8*)(bBase + (size_t)n2 * 512);
#pragma unroll
  for (int n2 = 0; n2 < 4; ++n2)
    bb1v[n2] = *(const f16x8*)(bBase + (size_t)(4 + n2) * 512);
  produce(w, 0);
  __syncthreads();

  f16x8 xab[2][4];
#pragma unroll
  for (int p = 0; p < 4; ++p) {
    const _Float16* buf = XB[p & 1];
#pragma unroll
    for (int mi = 0; mi < 4; ++mi)
      xab[0][mi] = *(const f16x8*)(buf + (size_t)mi * 512 + l * 8);
#pragma unroll
    for (int ktl = 0; ktl < 8; ++ktl) {
      int kt = p * 8 + ktl;
      if (ktl == w && p < 3) produce((p + 1) * 8 + w, (p & 1) ^ 1);
      if (ktl < 7) {
#pragma unroll
        for (int mi = 0; mi < 4; ++mi)
          xab[(ktl + 1) & 1][mi] =
              *(const f16x8*)(buf + (size_t)((ktl + 1) * 4 + mi) * 512 + l * 8);
      }
      __builtin_amdgcn_s_setprio(1);
#pragma unroll
      for (int mi = 0; mi < 4; ++mi)
#pragma unroll
        for (int n2 = 0; n2 < 4; ++n2)
          acc[mi][n2] = __builtin_amdgcn_mfma_f32_16x16x32_f16(
              bb0[n2], xab[ktl & 1][mi], acc[mi][n2], 0, 0, 0);
      if (kt < 31) {
#pragma unroll
        for (int n2 = 0; n2 < 4; ++n2)
          bb0[n2] = *(const f16x8*)(bBase + (size_t)((kt + 1) * 64 + n2) * 512);
      }
#pragma unroll
      for (int mi = 0; mi < 4; ++mi)
#pragma unroll
        for (int n2 = 0; n2 < 4; ++n2)
          acc[mi][4 + n2] = __builtin_amdgcn_mfma_f32_16x16x32_f16(
              bb1v[n2], xab[ktl & 1][mi], acc[mi][4 + n2], 0, 0, 0);
      if (kt < 31) {
#pragma unroll
        for (int n2 = 0; n2 < 4; ++n2)
          bb1v[n2] = *(const f16x8*)(bBase + (size_t)((kt + 1) * 64 + 4 + n2) * 512);
      }
      __builtin_amdgcn_s_setprio(0);
    }
    if (p < 3) __syncthreads();
  }

  // ---------------- fused q-network tail ----------------
  __syncthreads();  // all XB reads done before aliasing as x2h

  // pass A: waves 0..3 store tanh'd kc2 0..15 fragment tiles
  if (w < 4) {
#pragma unroll
    for (int mi = 0; mi < 4; ++mi)
#pragma unroll
      for (int p2 = 0; p2 < 4; ++p2) {
        int kc2 = w * 4 + p2;   // == nt0>>1 + p2, in [0,16)
        float sg2 = sigmoid_fast(g2[kc2]);
        f32x4 c0 = *(const f32x4*)(b2 + kc2 * 32 + q * 4);
        f32x4 c1 = *(const f32x4*)(b2 + kc2 * 32 + 16 + q * 4);
        f16x8 o;
#pragma unroll
        for (int r = 0; r < 4; ++r) {
          o[r]     = (_Float16)(tanh_fast(acc[mi][2 * p2][r] + c0[r]) * sg2);
          o[4 + r] = (_Float16)(tanh_fast(acc[mi][2 * p2 + 1][r] + c1[r]) * sg2);
        }
        *(f16x8*)(x2h + (size_t)(kc2 * 4 + mi) * 512 + l * 8) = o;
      }
  }
  __syncthreads();

  // q1 GEMM pass 0: kt 0..15
  f32x4 acc2[4][2] = {};
  for (int kt = 0; kt < 16; ++kt) {
    f16x8 a[4];
#pragma unroll
    for (int mi = 0; mi < 4; ++mi)
      a[mi] = *(const f16x8*)(x2h + (size_t)(kt * 4 + mi) * 512 + l * 8);
    f16x8 bf0 = *(const f16x8*)(t1p + (size_t)(kt * 16 + w * 2) * 512 + l * 8);
    f16x8 bf1 = *(const f16x8*)(t1p + (size_t)(kt * 16 + w * 2 + 1) * 512 + l * 8);
#pragma unroll
    for (int mi = 0; mi < 4; ++mi) {
      acc2[mi][0] = __builtin_amdgcn_mfma_f32_16x16x32_f16(a[mi], bf0, acc2[mi][0], 0, 0, 0);
      acc2[mi][1] = __builtin_amdgcn_mfma_f32_16x16x32_f16(a[mi], bf1, acc2[mi][1], 0, 0, 0);
    }
  }
  __syncthreads();

  // pass B: waves 4..7 store kc2 16..31
  if (w >= 4) {
#pragma unroll
    for (int mi = 0; mi < 4; ++mi)
#pragma unroll
      for (int p2 = 0; p2 < 4; ++p2) {
        int kc2 = w * 4 + p2;   // in [16,32)
        float sg2 = sigmoid_fast(g2[kc2]);
        f32x4 c0 = *(const f32x4*)(b2 + kc2 * 32 + q * 4);
        f32x4 c1 = *(const f32x4*)(b2 + kc2 * 32 + 16 + q * 4);
        f16x8 o;
#pragma unroll
        for (int r = 0; r < 4; ++r) {
          o[r]     = (_Float16)(tanh_fast(acc[mi][2 * p2][r] + c0[r]) * sg2);
          o[4 + r] = (_Float16)(tanh_fast(acc[mi][2 * p2 + 1][r] + c1[r]) * sg2);
        }
        *(f16x8*)(x2h + (size_t)((kc2 - 16) * 4 + mi) * 512 + l * 8) = o;
      }
  }
  __syncthreads();

  // q1 GEMM pass 1: kt 16..31
  for (int kt = 16; kt < 32; ++kt) {
    f16x8 a[4];
#pragma unroll
    for (int mi = 0; mi < 4; ++mi)
      a[mi] = *(const f16x8*)(x2h + (size_t)((kt - 16) * 4 + mi) * 512 + l * 8);
    f16x8 bf0 = *(const f16x8*)(t1p + (size_t)(kt * 16 + w * 2) * 512 + l * 8);
    f16x8 bf1 = *(const f16x8*)(t1p + (size_t)(kt * 16 + w * 2 + 1) * 512 + l * 8);
#pragma unroll
    for (int mi = 0; mi < 4; ++mi) {
      acc2[mi][0] = __builtin_amdgcn_mfma_f32_16x16x32_f16(a[mi], bf0, acc2[mi][0], 0, 0, 0);
      acc2[mi][1] = __builtin_amdgcn_mfma_f32_16x16x32_f16(a[mi], bf1, acc2[mi][1], 0, 0, 0);
    }
  }

  // bias + LN over 256 cols
#pragma unroll
  for (int ni = 0; ni < 2; ++ni) {
    int col = w * 32 + ni * 16 + l15;
    float b = bq1[col];
#pragma unroll
    for (int mi = 0; mi < 4; ++mi)
#pragma unroll
      for (int r = 0; r < 4; ++r) acc2[mi][ni][r] += b;
  }
#pragma unroll
  for (int mi = 0; mi < 4; ++mi)
#pragma unroll
    for (int r = 0; r < 4; ++r) {
      int row = mi * 16 + q * 4 + r;
      float s = 0.f, sq = 0.f;
#pragma unroll
      for (int ni = 0; ni < 2; ++ni) { float v = acc2[mi][ni][r]; s += v; sq += v * v; }
#pragma unroll
      for (int off = 1; off < 16; off <<= 1) { s += __shfl_xor(s, off); sq += __shfl_xor(sq, off); }
      if (l15 == 0) { redA[row * 8 + w] = s; redB[row * 8 + w] = sq; }
    }
  __syncthreads();
  if (t < 64) {
    float s = 0.f, sq = 0.f;
#pragma unroll
    for (int i = 0; i < 8; ++i) { s += redA[t * 8 + i]; sq += redB[t * 8 + i]; }
    float mean = s * (1.0f / 256.0f);
    float var = sq * (1.0f / 256.0f) - mean * mean;
    meanv[t] = mean; rstdv[t] = rsqrtf(var + 1e-5f);
  }
  __syncthreads();
#pragma unroll
  for (int mi = 0; mi < 4; ++mi)
#pragma unroll
    for (int ni = 0; ni < 2; ++ni)
#pragma unroll
      for (int r = 0; r < 4; ++r) {
        int row = mi * 16 + q * 4 + r;
        int col = w * 32 + ni * 16 + l15;
        float y = (acc2[mi][ni][r] - meanv[row]) * rstdv[row] * ln1g[col] + ln1b[col];
        y = fmaxf(y, 0.f);
        y1h[row * 264 + col] = (_Float16)y;
      }
  __syncthreads();

  // y2 GEMM: wave w owns cols w*16..w*16+15 (T2p tile nt=w, plain k-order)
  f32x4 a3[4] = {};
  for (int kt = 0; kt < 8; ++kt) {
    f16x8 af[4];
#pragma unroll
    for (int mi = 0; mi < 4; ++mi)
      af[mi] = *(const f16x8*)&y1h[(mi * 16 + l15) * 264 + kt * 32 + q * 8];
    f16x8 bf = *(const f16x8*)(t2p + (size_t)(w * 8 + kt) * 512 + l * 8);
#pragma unroll
    for (int mi = 0; mi < 4; ++mi)
      a3[mi] = __builtin_amdgcn_mfma_f32_16x16x32_f16(af[mi], bf, a3[mi], 0, 0, 0);
  }
  {
    int col = w * 16 + l15;
    float b = bq2[col];
#pragma unroll
    for (int mi = 0; mi < 4; ++mi)
#pragma unroll
      for (int r = 0; r < 4; ++r) a3[mi][r] += b;
  }
  __syncthreads();  // y1h reads done; redA/redB reuse safe
#pragma unroll
  for (int mi = 0; mi < 4; ++mi)
#pragma unroll
    for (int r = 0; r < 4; ++r) {
      int row = mi * 16 + q * 4 + r;
      float s = a3[mi][r], sq = s * s;
#pragma unroll
      for (int off = 1; off < 16; off <<= 1) { s += __shfl_xor(s, off); sq += __shfl_xor(sq, off); }
      if (l15 == 0) { redA[row * 8 + w] = s; redB[row * 8 + w] = sq; }
    }
  __syncthreads();
  if (t < 64) {
    float s = 0.f, sq = 0.f;
#pragma unroll
    for (int i = 0; i < 8; ++i) { s += redA[t * 8 + i]; sq += redB[t * 8 + i]; }
    float mean = s * (1.0f / 128.0f);
    float var = sq * (1.0f / 128.0f) - mean * mean;
    meanv[t] = mean; rstdv[t] = rsqrtf(var + 1e-5f);
  }
  __syncthreads();
#pragma unroll
  for (int mi = 0; mi < 4; ++mi)
#pragma unroll
    for (int r = 0; r < 4; ++r) {
      int row = mi * 16 + q * 4 + r;
      int col = w * 16 + l15;
      float y = (a3[mi][r] - meanv[row]) * rstdv[row] * ln2g[col] + ln2b[col];
      y = fmaxf(y, 0.f);
      float pr = y * wq3[col];
#pragma unroll
      for (int off = 1; off < 16; off <<= 1) pr += __shfl_xor(pr, off);
      if (l15 == 0) redA[row * 8 + w] = pr;
    }
  __syncthreads();
  if (t < 64) {
    float s = 0.f;
#pragma unroll
    for (int i = 0; i < 8; ++i) s += redA[t * 8 + i];
    out[m0 + t] = s + bq3[0];
  }
}

// ---------------- launcher ----------------
extern "C" void kernel_launch(void* const* d_in, const int* in_sizes, int n_in,
                              void* d_out, int out_size, void* d_ws, size_t ws_size,
                              hipStream_t stream) {
  const float* state  = (const float*)d_in[0];
  const float* action = (const float*)d_in[1];
  const float* W1  = (const float*)d_in[2];
  const float* b1  = (const float*)d_in[3];
  const float* g1  = (const float*)d_in[4];
  const float* W2  = (const float*)d_in[5];
  const float* b2  = (const float*)d_in[6];
  const float* g2  = (const float*)d_in[7];
  const float* Wq1 = (const float*)d_in[8];
  const float* bq1 = (const float*)d_in[9];
  const float* ln1g = (const float*)d_in[10];
  const float* ln1b = (const float*)d_in[11];
  const float* Wq2 = (const float*)d_in[12];
  const float* bq2 = (const float*)d_in[13];
  const float* ln2g = (const float*)d_in[14];
  const float* ln2b = (const float*)d_in[15];
  const float* Wq3 = (const float*)d_in[16];
  const float* bq3 = (const float*)d_in[17];
  int B = in_sizes[0] / 24;

  char* ws = (char*)d_ws;
  _Float16* V1p = (_Float16*)(ws);
  _Float16* V2p = (_Float16*)(ws + 65536);
  _Float16* T1p = (_Float16*)(ws + 65536 + 2097152);
  _Float16* T2p = (_Float16*)(ws + 65536 + 2097152 + 524288);

  prep_weights<<<2656, 256, 0, stream>>>(W1, W2, Wq1, Wq2, V1p, V2p, T1p, T2p);

  int nb = B / 64;
  k12q<<<dim3(nb), 512, 0, stream>>>(state, action, V1p, b1, g1,
                                     V2p, b2, g2, T1p, T2p,
                                     bq1, ln1g, ln1b, bq2, ln2g, ln2b,
                                     Wq3, bq3, (float*)d_out);
}

// Round 9
// 600.179 us; speedup vs baseline: 1.5589x; 1.5589x over previous
//
#include <hip/hip_runtime.h>
#include <hip/hip_bf16.h>

typedef _Float16 f16x8 __attribute__((ext_vector_type(8)));
typedef _Float16 f16x4 __attribute__((ext_vector_type(4)));
typedef float f32x4 __attribute__((ext_vector_type(4)));

__device__ __forceinline__ float tanh_fast(float x) {
  float e = __expf(2.0f * x);
  return 1.0f - 2.0f * __builtin_amdgcn_rcpf(e + 1.0f);
}
__device__ __forceinline__ float sigmoid_fast(float x) {
  return __builtin_amdgcn_rcpf(1.0f + __expf(-x));
}

// ---------------- K0: weight prep (unchanged) ----------------
// Fragment tiles of 512 hw. PI k-order (W2, Wq1): lane l elem j holds
// B[k = kt*32 + pi(q,j)][col = nt*16 + l15], pi(q,j) = q*4 + (j&3) + 16*(j>>2).
// Plain k-order (Wq2, W1): k = q*8 + j.
// V2p tile = kt*64 + nt; T1p tile = kt*16 + nt; T2p tile = nt*8 + kt.
__global__ __launch_bounds__(256) void prep_weights(
    const float* __restrict__ W1, const float* __restrict__ W2,
    const float* __restrict__ Wq1, const float* __restrict__ Wq2,
    _Float16* __restrict__ V1p, _Float16* __restrict__ V2p,
    _Float16* __restrict__ T1p, _Float16* __restrict__ T2p) {
  __shared__ float S[32 * 33];
  int b = blockIdx.x, t = threadIdx.x;
  if (b < 2624) {
    const float* in; _Float16* out; int N, nc0, tile, use_pi;
    if (b < 2048) {        // W2 [32][1024][32]: h, ntl, kt  (PI)
      int h = b >> 6, rem = b & 63, ntl = rem >> 5, kt = rem & 31;
      in = W2 + (size_t)h * 32768 + (size_t)kt * 32 * 32;
      N = 32; nc0 = ntl * 16;
      out = V2p; tile = kt * 64 + (h * 2 + ntl); use_pi = 1;
    } else if (b < 2560) { // Wq1 [1024][256]  (PI)
      int i = b - 2048, nt = i >> 5, kt = i & 31;
      in = Wq1 + (size_t)kt * 32 * 256; N = 256; nc0 = nt * 16;
      out = T1p; tile = kt * 16 + nt; use_pi = 1;
    } else {               // Wq2 [256][128]  (plain)
      int i = b - 2560, nt = i >> 3, kt = i & 7;
      in = Wq2 + (size_t)kt * 32 * 128; N = 128; nc0 = nt * 16;
      out = T2p; tile = nt * 8 + kt; use_pi = 0;
    }
    if (t < 128) {
      int r = t >> 2, c4 = (t & 3) * 4;
      const float4 v = *(const float4*)(in + (size_t)r * N + nc0 + c4);
      S[r * 17 + c4 + 0] = v.x; S[r * 17 + c4 + 1] = v.y;
      S[r * 17 + c4 + 2] = v.z; S[r * 17 + c4 + 3] = v.w;
    }
    __syncthreads();
    if (t < 128) {
      int w2 = t >> 6, l = t & 63, q = l >> 4, l15 = l & 15;
      f16x4 o;
#pragma unroll
      for (int jj = 0; jj < 4; ++jj) {
        int kl = use_pi ? (q * 4 + jj + w2 * 16) : (q * 8 + w2 * 4 + jj);
        o[jj] = (_Float16)S[kl * 17 + l15];
      }
      *(f16x4*)(out + (size_t)tile * 512 + l * 8 + w2 * 4) = o;
    }
  } else {                 // W1 [32][32][32]: one block per head h (plain)
    int h = b - 2624;
    const float* in = W1 + h * 1024;
    int cc = t & 31, rr8 = t >> 5;
#pragma unroll
    for (int p = 0; p < 4; ++p) {
      int r = rr8 + p * 8;
      S[cc * 33 + r] = in[r * 32 + cc];
    }
    __syncthreads();
    if (t < 128) {
      int ntl = t >> 6, l = t & 63, q = l >> 4, l15 = l & 15;
      f16x8 o;
#pragma unroll
      for (int j = 0; j < 8; ++j)
        o[j] = (_Float16)S[(ntl * 16 + l15) * 33 + q * 8 + j];
      *(f16x8*)(V1p + (size_t)(h * 2 + ntl) * 512 + l * 8) = o;
    }
  }
}

// ---------------- K12Q: fully fused ripple1+ripple2+q-network ----------------
// Block = 64 rows x 1024 cols, 512 threads = 8 waves. K-loop: round-6
// verbatim. TAIL (fixed vs round-8): after the K-loop ALL waves dump ALL
// their acc tiles (kc2 = w*4..w*4+3) into a full 128 KB x2h at once ->
// acc[4][8] (128 AGPRs) is DEAD before the q1 GEMM starts. Round-8 kept acc
// live across q1 (pass A/B split) -> 256-reg cap blown -> 279 MB scratch
// spill, whole kernel strangled (MfmaUtil 17%). LDS phase-aliasing of one
// 128 KB block: {SA 5K + XB 2x32K} (K-loop) -> x2h 128K (q1) -> y1h 33.8K
// (y2), each transition barrier-protected. Total LDS 132.5 KB, 1 block/CU.
// launch_bounds MUST stay (512,2) (reg cap: acc 128 AGPR + 128 VGPR).
__global__ __launch_bounds__(512, 2) void k12q(
    const float* __restrict__ state, const float* __restrict__ action,
    const _Float16* __restrict__ v1p, const float* __restrict__ b1,
    const float* __restrict__ g1,
    const _Float16* __restrict__ v2p, const float* __restrict__ b2,
    const float* __restrict__ g2,
    const _Float16* __restrict__ t1p, const _Float16* __restrict__ t2p,
    const float* __restrict__ bq1, const float* __restrict__ ln1g,
    const float* __restrict__ ln1b,
    const float* __restrict__ bq2, const float* __restrict__ ln2g,
    const float* __restrict__ ln2b,
    const float* __restrict__ wq3, const float* __restrict__ bq3,
    float* __restrict__ out) {
  __shared__ __align__(16) _Float16 LB[65536];           // 128 KB, phase-aliased
  __shared__ float redA[64 * 8], redB[64 * 8];           // 4 KB
  __shared__ float meanv[64], rstdv[64];                 // 0.5 KB
  _Float16* SA  = LB;                                    // 64*40 = 2560 (K-loop)
  _Float16* XBb = LB + 2560;                             // 2 x 16384 (K-loop)
  _Float16* x2h = LB;                                    // 128 tiles x 512 (tail q1)
  _Float16* y1h = LB;                                    // 64*264 (tail y2)

  int bm = blockIdx.x;
  int t = threadIdx.x, w = t >> 6, l = t & 63, q = l >> 4, l15 = l & 15;
  int m0 = bm * 64;

  {  // stage sa tile [64][32] fp16, stride 40; 8 threads/row (4 floats each)
    int r = t >> 3, qq = t & 7;
    size_t grow = (size_t)(m0 + r);
    const float* src = (qq < 6) ? (state + grow * 24 + qq * 4)
                                : (action + grow * 8 + (qq - 6) * 4);
    float4 v = *(const float4*)src;
    f16x4 h;
    h[0] = (_Float16)v.x; h[1] = (_Float16)v.y;
    h[2] = (_Float16)v.z; h[3] = (_Float16)v.w;
    *(f16x4*)&SA[r * 40 + qq * 4] = h;
  }
  __syncthreads();

  // loop-invariant sa fragments (B operand of producer MFMAs), 64 rows
  f16x8 asa[4];
#pragma unroll
  for (int p = 0; p < 4; ++p)
    asa[p] = *(const f16x8*)&SA[(p * 16 + l15) * 40 + q * 8];

  const int nt0 = w * 8;
  const _Float16* bBase = v2p + (size_t)nt0 * 512 + (size_t)l * 8;
  f32x4 acc[4][8] = {};

  auto produce = [&](int h, int buf) {
    f16x8 rb0 = *(const f16x8*)(v1p + (size_t)(2 * h) * 512 + l * 8);
    f16x8 rb1 = *(const f16x8*)(v1p + (size_t)(2 * h + 1) * 512 + l * 8);
    float sg = sigmoid_fast(g1[h]);
    f32x4 bs0 = *(const f32x4*)(b1 + h * 32 + q * 4);
    f32x4 bs1 = *(const f32x4*)(b1 + h * 32 + 16 + q * 4);
    _Float16* bw = XBb + (size_t)buf * 16384 + (size_t)((h & 7) * 4) * 512 + l * 8;
#pragma unroll
    for (int pp = 0; pp < 4; ++pp) {
      f32x4 d0 = {}, d1 = {};
      d0 = __builtin_amdgcn_mfma_f32_16x16x32_f16(rb0, asa[pp], d0, 0, 0, 0);
      d1 = __builtin_amdgcn_mfma_f32_16x16x32_f16(rb1, asa[pp], d1, 0, 0, 0);
      f16x8 o;
#pragma unroll
      for (int r = 0; r < 4; ++r) {
        o[r]     = (_Float16)(tanh_fast(d0[r] + bs0[r]) * sg);
        o[4 + r] = (_Float16)(tanh_fast(d1[r] + bs1[r]) * sg);
      }
      *(f16x8*)(bw + (size_t)pp * 512) = o;
    }
  };

  // prologue
  f16x8 bb0[4], bb1v[4];
#pragma unroll
  for (int n2 = 0; n2 < 4; ++n2)
    bb0[n2] = *(const f16x8*)(bBase + (size_t)n2 * 512);
#pragma unroll
  for (int n2 = 0; n2 < 4; ++n2)
    bb1v[n2] = *(const f16x8*)(bBase + (size_t)(4 + n2) * 512);
  produce(w, 0);
  __syncthreads();

  f16x8 xab[2][4];
#pragma unroll
  for (int p = 0; p < 4; ++p) {
    const _Float16* buf = XBb + (size_t)(p & 1) * 16384;
#pragma unroll
    for (int mi = 0; mi < 4; ++mi)
      xab[0][mi] = *(const f16x8*)(buf + (size_t)mi * 512 + l * 8);
#pragma unroll
    for (int ktl = 0; ktl < 8; ++ktl) {
      int kt = p * 8 + ktl;
      if (ktl == w && p < 3) produce((p + 1) * 8 + w, (p & 1) ^ 1);
      if (ktl < 7) {
#pragma unroll
        for (int mi = 0; mi < 4; ++mi)
          xab[(ktl + 1) & 1][mi] =
              *(const f16x8*)(buf + (size_t)((ktl + 1) * 4 + mi) * 512 + l * 8);
      }
      __builtin_amdgcn_s_setprio(1);
#pragma unroll
      for (int mi = 0; mi < 4; ++mi)
#pragma unroll
        for (int n2 = 0; n2 < 4; ++n2)
          acc[mi][n2] = __builtin_amdgcn_mfma_f32_16x16x32_f16(
              bb0[n2], xab[ktl & 1][mi], acc[mi][n2], 0, 0, 0);
      if (kt < 31) {
#pragma unroll
        for (int n2 = 0; n2 < 4; ++n2)
          bb0[n2] = *(const f16x8*)(bBase + (size_t)((kt + 1) * 64 + n2) * 512);
      }
#pragma unroll
      for (int mi = 0; mi < 4; ++mi)
#pragma unroll
        for (int n2 = 0; n2 < 4; ++n2)
          acc[mi][4 + n2] = __builtin_amdgcn_mfma_f32_16x16x32_f16(
              bb1v[n2], xab[ktl & 1][mi], acc[mi][4 + n2], 0, 0, 0);
      if (kt < 31) {
#pragma unroll
        for (int n2 = 0; n2 < 4; ++n2)
          bb1v[n2] = *(const f16x8*)(bBase + (size_t)((kt + 1) * 64 + 4 + n2) * 512);
      }
      __builtin_amdgcn_s_setprio(0);
    }
    if (p < 3) __syncthreads();
  }

  // ---------------- fused q-network tail ----------------
  __syncthreads();  // all XB reads done before aliasing LB as x2h

  // dump ALL acc tiles: wave w owns kc2 = w*4..w*4+3 -> x2h tile kc2*4+mi.
  // After this, acc is dead (frees 128 AGPRs for the tail).
#pragma unroll
  for (int mi = 0; mi < 4; ++mi)
#pragma unroll
    for (int p2 = 0; p2 < 4; ++p2) {
      int kc2 = w * 4 + p2;   // == nt0>>1 + p2
      float sg2 = sigmoid_fast(g2[kc2]);
      f32x4 c0 = *(const f32x4*)(b2 + kc2 * 32 + q * 4);
      f32x4 c1 = *(const f32x4*)(b2 + kc2 * 32 + 16 + q * 4);
      f16x8 o;
#pragma unroll
      for (int r = 0; r < 4; ++r) {
        o[r]     = (_Float16)(tanh_fast(acc[mi][2 * p2][r] + c0[r]) * sg2);
        o[4 + r] = (_Float16)(tanh_fast(acc[mi][2 * p2 + 1][r] + c1[r]) * sg2);
      }
      *(f16x8*)(x2h + (size_t)(kc2 * 4 + mi) * 512 + l * 8) = o;
    }
  __syncthreads();

  // q1 GEMM: kt 0..31, 1-deep prefetch of A (LDS) and B (L2) frags
  f32x4 acc2[4][2] = {};
  {
    f16x8 aC[4], aN[4], bf0C, bf1C, bf0N, bf1N;
#pragma unroll
    for (int mi = 0; mi < 4; ++mi)
      aC[mi] = *(const f16x8*)(x2h + (size_t)mi * 512 + l * 8);
    bf0C = *(const f16x8*)(t1p + (size_t)(w * 2) * 512 + l * 8);
    bf1C = *(const f16x8*)(t1p + (size_t)(w * 2 + 1) * 512 + l * 8);
#pragma unroll
    for (int kt = 0; kt < 32; ++kt) {
      if (kt < 31) {
#pragma unroll
        for (int mi = 0; mi < 4; ++mi)
          aN[mi] = *(const f16x8*)(x2h + (size_t)((kt + 1) * 4 + mi) * 512 + l * 8);
        bf0N = *(const f16x8*)(t1p + (size_t)((kt + 1) * 16 + w * 2) * 512 + l * 8);
        bf1N = *(const f16x8*)(t1p + (size_t)((kt + 1) * 16 + w * 2 + 1) * 512 + l * 8);
      }
#pragma unroll
      for (int mi = 0; mi < 4; ++mi) {
        acc2[mi][0] = __builtin_amdgcn_mfma_f32_16x16x32_f16(aC[mi], bf0C, acc2[mi][0], 0, 0, 0);
        acc2[mi][1] = __builtin_amdgcn_mfma_f32_16x16x32_f16(aC[mi], bf1C, acc2[mi][1], 0, 0, 0);
      }
#pragma unroll
      for (int mi = 0; mi < 4; ++mi) aC[mi] = aN[mi];
      bf0C = bf0N; bf1C = bf1N;
    }
  }

  // bias + LN over 256 cols
#pragma unroll
  for (int ni = 0; ni < 2; ++ni) {
    int col = w * 32 + ni * 16 + l15;
    float b = bq1[col];
#pragma unroll
    for (int mi = 0; mi < 4; ++mi)
#pragma unroll
      for (int r = 0; r < 4; ++r) acc2[mi][ni][r] += b;
  }
#pragma unroll
  for (int mi = 0; mi < 4; ++mi)
#pragma unroll
    for (int r = 0; r < 4; ++r) {
      int row = mi * 16 + q * 4 + r;
      float s = 0.f, sq = 0.f;
#pragma unroll
      for (int ni = 0; ni < 2; ++ni) { float v = acc2[mi][ni][r]; s += v; sq += v * v; }
#pragma unroll
      for (int off = 1; off < 16; off <<= 1) { s += __shfl_xor(s, off); sq += __shfl_xor(sq, off); }
      if (l15 == 0) { redA[row * 8 + w] = s; redB[row * 8 + w] = sq; }
    }
  __syncthreads();  // also: all x2h reads complete past this point
  if (t < 64) {
    float s = 0.f, sq = 0.f;
#pragma unroll
    for (int i = 0; i < 8; ++i) { s += redA[t * 8 + i]; sq += redB[t * 8 + i]; }
    float mean = s * (1.0f / 256.0f);
    float var = sq * (1.0f / 256.0f) - mean * mean;
    meanv[t] = mean; rstdv[t] = rsqrtf(var + 1e-5f);
  }
  __syncthreads();
#pragma unroll
  for (int mi = 0; mi < 4; ++mi)
#pragma unroll
    for (int ni = 0; ni < 2; ++ni)
#pragma unroll
      for (int r = 0; r < 4; ++r) {
        int row = mi * 16 + q * 4 + r;
        int col = w * 32 + ni * 16 + l15;
        float y = (acc2[mi][ni][r] - meanv[row]) * rstdv[row] * ln1g[col] + ln1b[col];
        y = fmaxf(y, 0.f);
        y1h[row * 264 + col] = (_Float16)y;   // y1h aliases LB (x2h dead)
      }
  __syncthreads();

  // y2 GEMM: wave w owns cols w*16..w*16+15 (T2p tile nt=w, plain k-order)
  f32x4 a3[4] = {};
  for (int kt = 0; kt < 8; ++kt) {
    f16x8 af[4];
#pragma unroll
    for (int mi = 0; mi < 4; ++mi)
      af[mi] = *(const f16x8*)&y1h[(mi * 16 + l15) * 264 + kt * 32 + q * 8];
    f16x8 bf = *(const f16x8*)(t2p + (size_t)(w * 8 + kt) * 512 + l * 8);
#pragma unroll
    for (int mi = 0; mi < 4; ++mi)
      a3[mi] = __builtin_amdgcn_mfma_f32_16x16x32_f16(af[mi], bf, a3[mi], 0, 0, 0);
  }
  {
    int col = w * 16 + l15;
    float b = bq2[col];
#pragma unroll
    for (int mi = 0; mi < 4; ++mi)
#pragma unroll
      for (int r = 0; r < 4; ++r) a3[mi][r] += b;
  }
  __syncthreads();  // y1h reads done; redA/redB reuse safe
#pragma unroll
  for (int mi = 0; mi < 4; ++mi)
#pragma unroll
    for (int r = 0; r < 4; ++r) {
      int row = mi * 16 + q * 4 + r;
      float s = a3[mi][r], sq = s * s;
#pragma unroll
      for (int off = 1; off < 16; off <<= 1) { s += __shfl_xor(s, off); sq += __shfl_xor(sq, off); }
      if (l15 == 0) { redA[row * 8 + w] = s; redB[row * 8 + w] = sq; }
    }
  __syncthreads();
  if (t < 64) {
    float s = 0.f, sq = 0.f;
#pragma unroll
    for (int i = 0; i < 8; ++i) { s += redA[t * 8 + i]; sq += redB[t * 8 + i]; }
    float mean = s * (1.0f / 128.0f);
    float var = sq * (1.0f / 128.0f) - mean * mean;
    meanv[t] = mean; rstdv[t] = rsqrtf(var + 1e-5f);
  }
  __syncthreads();
#pragma unroll
  for (int mi = 0; mi < 4; ++mi)
#pragma unroll
    for (int r = 0; r < 4; ++r) {
      int row = mi * 16 + q * 4 + r;
      int col = w * 16 + l15;
      float y = (a3[mi][r] - meanv[row]) * rstdv[row] * ln2g[col] + ln2b[col];
      y = fmaxf(y, 0.f);
      float pr = y * wq3[col];
#pragma unroll
      for (int off = 1; off < 16; off <<= 1) pr += __shfl_xor(pr, off);
      if (l15 == 0) redA[row * 8 + w] = pr;
    }
  __syncthreads();
  if (t < 64) {
    float s = 0.f;
#pragma unroll
    for (int i = 0; i < 8; ++i) s += redA[t * 8 + i];
    out[m0 + t] = s + bq3[0];
  }
}

// ---------------- launcher ----------------
extern "C" void kernel_launch(void* const* d_in, const int* in_sizes, int n_in,
                              void* d_out, int out_size, void* d_ws, size_t ws_size,
                              hipStream_t stream) {
  const float* state  = (const float*)d_in[0];
  const float* action = (const float*)d_in[1];
  const float* W1  = (const float*)d_in[2];
  const float* b1  = (const float*)d_in[3];
  const float* g1  = (const float*)d_in[4];
  const float* W2  = (const float*)d_in[5];
  const float* b2  = (const float*)d_in[6];
  const float* g2  = (const float*)d_in[7];
  const float* Wq1 = (const float*)d_in[8];
  const float* bq1 = (const float*)d_in[9];
  const float* ln1g = (const float*)d_in[10];
  const float* ln1b = (const float*)d_in[11];
  const float* Wq2 = (const float*)d_in[12];
  const float* bq2 = (const float*)d_in[13];
  const float* ln2g = (const float*)d_in[14];
  const float* ln2b = (const float*)d_in[15];
  const float* Wq3 = (const float*)d_in[16];
  const float* bq3 = (const float*)d_in[17];
  int B = in_sizes[0] / 24;

  char* ws = (char*)d_ws;
  _Float16* V1p = (_Float16*)(ws);
  _Float16* V2p = (_Float16*)(ws + 65536);
  _Float16* T1p = (_Float16*)(ws + 65536 + 2097152);
  _Float16* T2p = (_Float16*)(ws + 65536 + 2097152 + 524288);

  prep_weights<<<2656, 256, 0, stream>>>(W1, W2, Wq1, Wq2, V1p, V2p, T1p, T2p);

  int nb = B / 64;
  k12q<<<dim3(nb), 512, 0, stream>>>(state, action, V1p, b1, g1,
                                     V2p, b2, g2, T1p, T2p,
                                     bq1, ln1g, ln1b, bq2, ln2g, ln2b,
                                     Wq3, bq3, (float*)d_out);
}